// Round 3
// baseline (14120.737 us; speedup 1.0000x reference)
//
#include <hip/hip_runtime.h>
#include <stdint.h>
#include <math.h>

// ---------------------------------------------------------------------------
// QuantumDiffusionDreamer — round 3: fused/batched bf16 MFMA pipeline
// Per step (5 dispatches):
//   G1: qf  = relu(x @ Wq + bq)                      [8192,1024] 512 blocks
//   G2: h01 = relu|tanh(qf @ [W01|W11] + [b01|b11])  [8192,2048] 1024 blocks
//   G3: d01 = {h0@W02+b02, h1@W12+b12} (z-batched)   [8192,1024] 512 blocks
//   G4: hi  = gelu(d01 @ Wi1 + bi1)                  [8192,1024] 512 blocks
//   G5: itf = hi @ Wi2 + bi2, fused DDPM update of x [8192,512]  256 blocks
// PRNG: JAX threefry2x32 partitionable (verified r1/r2). x stays fp32.
// ---------------------------------------------------------------------------

typedef __bf16 bf16x8 __attribute__((ext_vector_type(8)));
typedef float floatx4 __attribute__((ext_vector_type(4)));

__host__ __device__ inline void tf2x32(uint32_t k0, uint32_t k1,
                                       uint32_t x0, uint32_t x1,
                                       uint32_t& o0, uint32_t& o1) {
  uint32_t ks2 = k0 ^ k1 ^ 0x1BD11BDAu;
#define TF_R(r) { x0 += x1; x1 = (x1 << (r)) | (x1 >> (32 - (r))); x1 ^= x0; }
  x0 += k0; x1 += k1;
  TF_R(13) TF_R(15) TF_R(26) TF_R(6)
  x0 += k1;  x1 += ks2 + 1u;
  TF_R(17) TF_R(29) TF_R(16) TF_R(24)
  x0 += ks2; x1 += k0 + 2u;
  TF_R(13) TF_R(15) TF_R(26) TF_R(6)
  x0 += k0;  x1 += k1 + 3u;
  TF_R(17) TF_R(29) TF_R(16) TF_R(24)
  x0 += k1;  x1 += ks2 + 4u;
  TF_R(13) TF_R(15) TF_R(26) TF_R(6)
  x0 += ks2; x1 += k0 + 5u;
#undef TF_R
  o0 = x0; o1 = x1;
}

__device__ inline float erfinv_f32(float x) {
  float w = -log1pf(-x * x);
  float p;
  if (w < 5.0f) {
    w = w - 2.5f;
    p = 2.81022636e-08f;
    p = fmaf(p, w, 3.43273939e-07f);
    p = fmaf(p, w, -3.5233877e-06f);
    p = fmaf(p, w, -4.39150654e-06f);
    p = fmaf(p, w, 0.00021858087f);
    p = fmaf(p, w, -0.00125372503f);
    p = fmaf(p, w, -0.00417768164f);
    p = fmaf(p, w, 0.246640727f);
    p = fmaf(p, w, 1.50140941f);
  } else {
    w = sqrtf(w) - 3.0f;
    p = -0.000200214257f;
    p = fmaf(p, w, 0.000100950558f);
    p = fmaf(p, w, 0.00134934322f);
    p = fmaf(p, w, -0.00367342844f);
    p = fmaf(p, w, 0.00573950773f);
    p = fmaf(p, w, -0.0076224613f);
    p = fmaf(p, w, 0.00943887047f);
    p = fmaf(p, w, 1.00167406f);
    p = fmaf(p, w, 2.83297682f);
  }
  return p * x;
}

__device__ inline float tf_normal(uint32_t k0, uint32_t k1, uint32_t i) {
  uint32_t o0, o1;
  tf2x32(k0, k1, 0u, i, o0, o1);
  uint32_t bits = o0 ^ o1;  // partitionable random_bits path
  float f = __uint_as_float(0x3F800000u | (bits >> 9)) - 1.0f;  // [0,1)
  float u = f * 2.0f + (-0.99999994f);
  u = fmaxf(-0.99999994f, u);
  return 1.41421356f * erfinv_f32(u);
}

__device__ inline unsigned short f2bf(float f) {
  uint32_t u = __float_as_uint(f);
  u += 0x7FFFu + ((u >> 16) & 1u);   // round-to-nearest-even
  return (unsigned short)(u >> 16);
}
__device__ inline float bf2f(unsigned short h) {
  return __uint_as_float(((uint32_t)h) << 16);
}

// ---------------------------------------------------------------------------
// Weight transpose + bf16 convert: Wt[n][k] = bf16(W[k][n]);  W is [K,N] fp32.
// ---------------------------------------------------------------------------
__global__ __launch_bounds__(256)
void transpose_bf16_kernel(const float* __restrict__ W,
                           unsigned short* __restrict__ Wt, int K, int N) {
  __shared__ float tile[32][33];
  int kb = blockIdx.x * 32, nb = blockIdx.y * 32;
  int tx = threadIdx.x & 31, ty = threadIdx.x >> 5;
#pragma unroll
  for (int i = 0; i < 32; i += 8)
    tile[ty + i][tx] = W[(size_t)(kb + ty + i) * N + nb + tx];
  __syncthreads();
#pragma unroll
  for (int i = 0; i < 32; i += 8)
    Wt[(size_t)(nb + ty + i) * K + kb + tx] = f2bf(tile[tx][ty + i]);
}

// ---------------------------------------------------------------------------
// Shared MFMA core: 128x128 tile, BK=32, 4 waves (2x2 of 64x64), 16x16x32.
// A: row-major [.,lda] bf16 (lda >= Ktot allows strided views).
// Bt: [N][Ktot] bf16 row-major (weights pre-transposed).
// ---------------------------------------------------------------------------
__device__ __forceinline__ void gemm_core(
    const unsigned short* __restrict__ A, int lda, int Ktot,
    const unsigned short* __restrict__ Bt, int row0, int col0,
    unsigned short* As, unsigned short* Bs, floatx4 (&acc)[4][4]) {
  const int tid = threadIdx.x;
  const int wave = tid >> 6, lane = tid & 63;
  const int wr = wave >> 1, wc = wave & 1;
  const int lrow = lane >> 2, lk = (lane & 3) * 8;
  const int fm = lane & 15, quad = lane >> 4;

  for (int k0 = 0; k0 < Ktot; k0 += 32) {
#pragma unroll
    for (int r = 0; r < 2; r++) {
      int srow = r * 64 + wave * 16 + lrow;   // lane-contiguous LDS order
      __builtin_amdgcn_global_load_lds(
          (const __attribute__((address_space(1))) uint32_t*)
              (A + (size_t)(row0 + srow) * lda + k0 + lk),
          (__attribute__((address_space(3))) uint32_t*)(As + srow * 32 + lk),
          16, 0, 0);
      __builtin_amdgcn_global_load_lds(
          (const __attribute__((address_space(1))) uint32_t*)
              (Bt + (size_t)(col0 + srow) * Ktot + k0 + lk),
          (__attribute__((address_space(3))) uint32_t*)(Bs + srow * 32 + lk),
          16, 0, 0);
    }
    __syncthreads();

    bf16x8 a[4], b[4];
#pragma unroll
    for (int u = 0; u < 4; u++)
      a[u] = *(const bf16x8*)(As + (wr * 64 + u * 16 + fm) * 32 + quad * 8);
#pragma unroll
    for (int v = 0; v < 4; v++)
      b[v] = *(const bf16x8*)(Bs + (wc * 64 + v * 16 + fm) * 32 + quad * 8);
#pragma unroll
    for (int u = 0; u < 4; u++)
#pragma unroll
      for (int v = 0; v < 4; v++)
        acc[u][v] = __builtin_amdgcn_mfma_f32_16x16x32_bf16(a[u], b[v],
                                                            acc[u][v], 0, 0, 0);
    __syncthreads();
  }
}

// ACT: 0 none, 1 relu, 3 gelu(exact), 4 relu(col<nsplit)|tanh with dual bias
template<int ACT>
__global__ __launch_bounds__(256)
void mfma_gemm(const unsigned short* __restrict__ A, int lda, int Ktot,
               const unsigned short* __restrict__ Bt,
               const float* __restrict__ bias,
               const float* __restrict__ bias1, int nsplit,
               unsigned short* __restrict__ C, int ldc) {
  __shared__ unsigned short As[128 * 32];
  __shared__ unsigned short Bs[128 * 32];
  const int row0 = blockIdx.y * 128, col0 = blockIdx.x * 128;
  floatx4 acc[4][4];
#pragma unroll
  for (int u = 0; u < 4; u++)
#pragma unroll
    for (int v = 0; v < 4; v++) acc[u][v] = (floatx4){0.f, 0.f, 0.f, 0.f};
  gemm_core(A, lda, Ktot, Bt, row0, col0, As, Bs, acc);

  const int lane = threadIdx.x & 63, wave = threadIdx.x >> 6;
  const int wr = wave >> 1, wc = wave & 1;
  const int fm = lane & 15, quad = lane >> 4;
#pragma unroll
  for (int v = 0; v < 4; v++) {
    int col = col0 + wc * 64 + v * 16 + fm;
    bool lo = (ACT != 4) || (col < nsplit);
    float bv = (ACT == 4) ? (lo ? bias[col] : bias1[col - nsplit]) : bias[col];
#pragma unroll
    for (int u = 0; u < 4; u++) {
      int rbase = row0 + wr * 64 + u * 16 + quad * 4;
#pragma unroll
      for (int r = 0; r < 4; r++) {
        float val = acc[u][v][r] + bv;
        if (ACT == 1) val = fmaxf(val, 0.0f);
        if (ACT == 3) val = 0.5f * val * (1.0f + erff(val * 0.70710678118654752f));
        if (ACT == 4) val = lo ? fmaxf(val, 0.0f) : tanhf(val);
        C[(size_t)(rbase + r) * ldc + col] = f2bf(val);
      }
    }
  }
}

// z-batched pair: z=0: d01[:, :512] = h01[:, :1024]@W02+b02
//                 z=1: d01[:, 512:] = h01[:, 1024:]@W12+b12
__global__ __launch_bounds__(256)
void mfma_gemm_dual(const unsigned short* __restrict__ h01,
                    const unsigned short* __restrict__ Bt0,
                    const unsigned short* __restrict__ Bt1,
                    const float* __restrict__ bias0,
                    const float* __restrict__ bias1,
                    unsigned short* __restrict__ d01) {
  __shared__ unsigned short As[128 * 32];
  __shared__ unsigned short Bs[128 * 32];
  const int z = blockIdx.z;
  const unsigned short* A = h01 + (size_t)z * 1024;
  const unsigned short* Bt = z ? Bt1 : Bt0;
  const float* bias = z ? bias1 : bias0;
  unsigned short* C = d01 + (size_t)z * 512;
  const int row0 = blockIdx.y * 128, col0 = blockIdx.x * 128;
  floatx4 acc[4][4];
#pragma unroll
  for (int u = 0; u < 4; u++)
#pragma unroll
    for (int v = 0; v < 4; v++) acc[u][v] = (floatx4){0.f, 0.f, 0.f, 0.f};
  gemm_core(A, 2048, 1024, Bt, row0, col0, As, Bs, acc);

  const int lane = threadIdx.x & 63, wave = threadIdx.x >> 6;
  const int wr = wave >> 1, wc = wave & 1;
  const int fm = lane & 15, quad = lane >> 4;
#pragma unroll
  for (int v = 0; v < 4; v++) {
    int col = col0 + wc * 64 + v * 16 + fm;
    float bv = bias[col];
#pragma unroll
    for (int u = 0; u < 4; u++) {
      int rbase = row0 + wr * 64 + u * 16 + quad * 4;
#pragma unroll
      for (int r = 0; r < 4; r++)
        C[(size_t)(rbase + r) * 1024 + col] = f2bf(acc[u][v][r] + bv);
    }
  }
}

// G5: itf = hi @ Wi2 + bi2 fused with the DDPM x-update (writes x fp32 + xbf)
__global__ __launch_bounds__(256)
void mfma_gemm_update(const unsigned short* __restrict__ A,   // hi [8192,1024]
                      const unsigned short* __restrict__ Bt,  // Wi2_t [512][1024]
                      const float* __restrict__ bias,
                      const unsigned short* __restrict__ d01,
                      float* __restrict__ x,
                      unsigned short* __restrict__ xbf,
                      const float* __restrict__ a_amp,
                      const float* __restrict__ b_amp,
                      const float* __restrict__ ph,
                      float coh, float c1, float sqa, float sigma,
                      int add_noise, uint32_t k0, uint32_t k1) {
  __shared__ unsigned short As[128 * 32];
  __shared__ unsigned short Bs[128 * 32];
  const int row0 = blockIdx.y * 128, col0 = blockIdx.x * 128;
  floatx4 acc[4][4];
#pragma unroll
  for (int u = 0; u < 4; u++)
#pragma unroll
    for (int v = 0; v < 4; v++) acc[u][v] = (floatx4){0.f, 0.f, 0.f, 0.f};
  gemm_core(A, 1024, 1024, Bt, row0, col0, As, Bs, acc);

  float aa = a_amp[0], bb = b_amp[0], pc = ph[0];
  float a2 = aa * aa, b2 = bb * bb, s = a2 + b2;
  float p0 = a2 / s, p1 = b2 / s;
  float sp0 = sqrtf(p0), sp1 = sqrtf(p1);
  float qi = 2.0f * sqrtf(p0 * p1) * pc * coh;
  float nscale = sigma + 0.1f * fabsf(qi);

  const int lane = threadIdx.x & 63, wave = threadIdx.x >> 6;
  const int wr = wave >> 1, wc = wave & 1;
  const int fm = lane & 15, quad = lane >> 4;
#pragma unroll
  for (int v = 0; v < 4; v++) {
    int col = col0 + wc * 64 + v * 16 + fm;
    float bv = bias[col];
#pragma unroll
    for (int u = 0; u < 4; u++) {
      int rbase = row0 + wr * 64 + u * 16 + quad * 4;
#pragma unroll
      for (int r = 0; r < 4; r++) {
        int row = rbase + r;
        float itf = acc[u][v][r] + bv;
        float dv0 = bf2f(d01[(size_t)row * 1024 + col]);
        float dv1 = bf2f(d01[(size_t)row * 1024 + 512 + col]);
        float den = sp0 * dv0 + sp1 * dv1 + qi * itf;
        size_t xi = (size_t)row * 512 + col;
        float xn = (x[xi] - c1 * den) / sqa;
        if (add_noise) xn += nscale * tf_normal(k0, k1, (uint32_t)xi);
        x[xi] = xn;
        xbf[xi] = f2bf(xn);
      }
    }
  }
}

__global__ void init_normal_kernel(float* __restrict__ x,
                                   unsigned short* __restrict__ xbf,
                                   uint32_t k0, uint32_t k1, int n) {
  int i = blockIdx.x * blockDim.x + threadIdx.x;
  if (i >= n) return;
  float v = tf_normal(k0, k1, (uint32_t)i);
  x[i] = v;
  xbf[i] = f2bf(v);
}

__global__ void final_kernel(const float* __restrict__ x,
                             const float* __restrict__ real,
                             float* __restrict__ out,
                             const float* __restrict__ a_amp,
                             const float* __restrict__ b_amp,
                             uint32_t k0, uint32_t k1, int n) {
  int i = blockIdx.x * blockDim.x + threadIdx.x;
  if (i >= n) return;
  float aa = a_amp[0], bb = b_amp[0];
  float a2 = aa * aa, b2 = bb * bb;
  float p0 = a2 / (a2 + b2);
  uint32_t o0, o1;
  tf2x32(k0, k1, 0u, 0u, o0, o1);
  uint32_t bits = o0 ^ o1;
  float u = __uint_as_float(0x3F800000u | (bits >> 9)) - 1.0f;
  float xv = x[i];
  out[i] = (u < p0) ? (0.7f * xv + 0.3f * real[i]) : xv;
}

extern "C" void kernel_launch(void* const* d_in, const int* in_sizes, int n_in,
                              void* d_out, int out_size, void* d_ws,
                              size_t ws_size, hipStream_t stream) {
  const float* real = (const float*)d_in[0];
  const float* Wq  = (const float*)d_in[2];
  const float* bq  = (const float*)d_in[3];
  const float* W01 = (const float*)d_in[4];
  const float* b01 = (const float*)d_in[5];
  const float* W02 = (const float*)d_in[6];
  const float* b02 = (const float*)d_in[7];
  const float* W11 = (const float*)d_in[8];
  const float* b11 = (const float*)d_in[9];
  const float* W12 = (const float*)d_in[10];
  const float* b12 = (const float*)d_in[11];
  const float* Wi1 = (const float*)d_in[12];
  const float* bi1 = (const float*)d_in[13];
  const float* Wi2 = (const float*)d_in[14];
  const float* bi2 = (const float*)d_in[15];
  const float* a_amp = (const float*)d_in[16];
  const float* b_amp = (const float*)d_in[17];
  const float* ph    = (const float*)d_in[18];

  const int Nn = 8192, F = 512, H = 1024;
  const int nElem = Nn * F;  // 4,194,304

  // workspace layout (~100 MB)
  char* ws = (char*)d_ws;
  float* x = (float*)ws;                        ws += (size_t)nElem * 4;
  unsigned short* xbf = (unsigned short*)ws;    ws += (size_t)nElem * 2;
  unsigned short* qf  = (unsigned short*)ws;    ws += (size_t)Nn * H * 2;   // also hi
  unsigned short* h01 = (unsigned short*)ws;    ws += (size_t)Nn * 2 * H * 2;
  unsigned short* d01 = (unsigned short*)ws;    ws += (size_t)Nn * H * 2;
  unsigned short* Wq_t  = (unsigned short*)ws;  ws += (size_t)F * H * 2;
  unsigned short* WA_t  = (unsigned short*)ws;  ws += (size_t)(2 * H) * H * 2; // [W01|W11]
  unsigned short* W02_t = (unsigned short*)ws;  ws += (size_t)H * F * 2;
  unsigned short* W12_t = (unsigned short*)ws;  ws += (size_t)H * F * 2;
  unsigned short* Wi1_t = (unsigned short*)ws;  ws += (size_t)(2 * F) * H * 2;
  unsigned short* Wi2_t = (unsigned short*)ws;  ws += (size_t)H * F * 2;

  dim3 tb(256);
  transpose_bf16_kernel<<<dim3(F / 32, H / 32), tb, 0, stream>>>(Wq, Wq_t, F, H);
  transpose_bf16_kernel<<<dim3(H / 32, H / 32), tb, 0, stream>>>(W01, WA_t, H, H);
  transpose_bf16_kernel<<<dim3(H / 32, H / 32), tb, 0, stream>>>(W11, WA_t + (size_t)H * H, H, H);
  transpose_bf16_kernel<<<dim3(H / 32, F / 32), tb, 0, stream>>>(W02, W02_t, H, F);
  transpose_bf16_kernel<<<dim3(H / 32, F / 32), tb, 0, stream>>>(W12, W12_t, H, F);
  transpose_bf16_kernel<<<dim3(2 * F / 32, H / 32), tb, 0, stream>>>(Wi1, Wi1_t, 2 * F, H);
  transpose_bf16_kernel<<<dim3(H / 32, F / 32), tb, 0, stream>>>(Wi2, Wi2_t, H, F);

  uint32_t kx0, kx1; tf2x32(0u, 1u, 0u, 10000u, kx0, kx1);
  init_normal_kernel<<<(nElem + 255) / 256, 256, 0, stream>>>(x, xbf, kx0, kx1, nElem);

  float sched[100];
  for (int i = 0; i < 100; i++)
    sched[i] = (float)(1e-4 + (0.02 - 1e-4) * (double)i / 99.0);
  const float decay = expf(-0.1f);
  float coh = 1.0f;

  dim3 blk(256);
  dim3 g1(H / 128, Nn / 128);          // 512 blocks
  dim3 g2(2 * H / 128, Nn / 128);      // 1024 blocks
  dim3 g3(F / 128, Nn / 128, 2);       // 512 blocks
  dim3 g4(H / 128, Nn / 128);          // 512 blocks
  dim3 g5(F / 128, Nn / 128);          // 256 blocks

  for (int j = 0; j < 50; j++) {
    int t = 49 - j;
    // G1: qf = relu(x @ Wq + bq)
    mfma_gemm<1><<<g1, blk, 0, stream>>>(xbf, F, F, Wq_t, bq, nullptr, 0, qf, H);
    // G2: h01 = relu|tanh(qf @ [W01|W11] + [b01|b11])
    mfma_gemm<4><<<g2, blk, 0, stream>>>(qf, H, H, WA_t, b01, b11, H, h01, 2 * H);
    // G3: d01 = {h0@W02+b02, h1@W12+b12}
    mfma_gemm_dual<<<g3, blk, 0, stream>>>(h01, W02_t, W12_t, b02, b12, d01);
    // G4: hi(=qf) = gelu(d01 @ Wi1 + bi1)
    mfma_gemm<3><<<g4, blk, 0, stream>>>(d01, H, H, Wi1_t, bi1, nullptr, 0, qf, H);

    float schedt = sched[t];
    float alphaf = fmaxf(1.0f - schedt, 1e-8f);
    float one_m_alpha = 1.0f - alphaf;
    float sqrt_1ma = sqrtf(fmaxf(one_m_alpha, 1e-8f));
    float c1 = one_m_alpha / sqrt_1ma;
    float sqa = sqrtf(alphaf);
    float sigma = 0.0f;
    if (t > 0) {
      float ap = 1.0f - sched[t - 1];
      sigma = sqrtf(fmaxf((1.0f - ap) / one_m_alpha * (1.0f - alphaf / ap), 0.0f));
    }
    uint32_t kt0, kt1; tf2x32(0u, 1u, 0u, (uint32_t)t, kt0, kt1);
    // G5: itf = hi @ Wi2 + bi2, fused DDPM update
    mfma_gemm_update<<<g5, blk, 0, stream>>>(
        qf, Wi2_t, bi2, d01, x, xbf, a_amp, b_amp, ph, coh, c1, sqa, sigma,
        (t > 0) ? 1 : 0, kt0, kt1);
    coh *= decay;
  }

  uint32_t ku0, ku1; tf2x32(0u, 1u, 0u, 99999u, ku0, ku1);
  final_kernel<<<(nElem + 255) / 256, 256, 0, stream>>>(
      x, real, (float*)d_out, a_amp, b_amp, ku0, ku1, nElem);
}

// Round 4
// 11070.201 us; speedup vs baseline: 1.2756x; 1.2756x over previous
//
#include <hip/hip_runtime.h>
#include <stdint.h>
#include <math.h>

// ---------------------------------------------------------------------------
// QuantumDiffusionDreamer — round 4: r2 structure (measured 11.7 ms) with
// explicitly double-buffered MFMA K-loop (raw s_waitcnt vmcnt(4)+s_barrier,
// m139-style) to hide the global_load_lds drain at 1-2 blocks/CU occupancy.
// PRNG: JAX threefry2x32 partitionable (verified r1-r3). x stays fp32.
// ---------------------------------------------------------------------------

typedef __bf16 bf16x8 __attribute__((ext_vector_type(8)));
typedef float floatx4 __attribute__((ext_vector_type(4)));

__host__ __device__ inline void tf2x32(uint32_t k0, uint32_t k1,
                                       uint32_t x0, uint32_t x1,
                                       uint32_t& o0, uint32_t& o1) {
  uint32_t ks2 = k0 ^ k1 ^ 0x1BD11BDAu;
#define TF_R(r) { x0 += x1; x1 = (x1 << (r)) | (x1 >> (32 - (r))); x1 ^= x0; }
  x0 += k0; x1 += k1;
  TF_R(13) TF_R(15) TF_R(26) TF_R(6)
  x0 += k1;  x1 += ks2 + 1u;
  TF_R(17) TF_R(29) TF_R(16) TF_R(24)
  x0 += ks2; x1 += k0 + 2u;
  TF_R(13) TF_R(15) TF_R(26) TF_R(6)
  x0 += k0;  x1 += k1 + 3u;
  TF_R(17) TF_R(29) TF_R(16) TF_R(24)
  x0 += k1;  x1 += ks2 + 4u;
  TF_R(13) TF_R(15) TF_R(26) TF_R(6)
  x0 += ks2; x1 += k0 + 5u;
#undef TF_R
  o0 = x0; o1 = x1;
}

__device__ inline float erfinv_f32(float x) {
  float w = -log1pf(-x * x);
  float p;
  if (w < 5.0f) {
    w = w - 2.5f;
    p = 2.81022636e-08f;
    p = fmaf(p, w, 3.43273939e-07f);
    p = fmaf(p, w, -3.5233877e-06f);
    p = fmaf(p, w, -4.39150654e-06f);
    p = fmaf(p, w, 0.00021858087f);
    p = fmaf(p, w, -0.00125372503f);
    p = fmaf(p, w, -0.00417768164f);
    p = fmaf(p, w, 0.246640727f);
    p = fmaf(p, w, 1.50140941f);
  } else {
    w = sqrtf(w) - 3.0f;
    p = -0.000200214257f;
    p = fmaf(p, w, 0.000100950558f);
    p = fmaf(p, w, 0.00134934322f);
    p = fmaf(p, w, -0.00367342844f);
    p = fmaf(p, w, 0.00573950773f);
    p = fmaf(p, w, -0.0076224613f);
    p = fmaf(p, w, 0.00943887047f);
    p = fmaf(p, w, 1.00167406f);
    p = fmaf(p, w, 2.83297682f);
  }
  return p * x;
}

__device__ inline float tf_normal(uint32_t k0, uint32_t k1, uint32_t i) {
  uint32_t o0, o1;
  tf2x32(k0, k1, 0u, i, o0, o1);
  uint32_t bits = o0 ^ o1;  // partitionable random_bits path
  float f = __uint_as_float(0x3F800000u | (bits >> 9)) - 1.0f;  // [0,1)
  float u = f * 2.0f + (-0.99999994f);
  u = fmaxf(-0.99999994f, u);
  return 1.41421356f * erfinv_f32(u);
}

__device__ inline unsigned short f2bf(float f) {
  uint32_t u = __float_as_uint(f);
  u += 0x7FFFu + ((u >> 16) & 1u);   // round-to-nearest-even
  return (unsigned short)(u >> 16);
}
__device__ inline float bf2f(unsigned short h) {
  return __uint_as_float(((uint32_t)h) << 16);
}

// ---------------------------------------------------------------------------
// Weight transpose + bf16 convert: Wt[n][k] = bf16(W[k][n]);  W is [K,N] fp32.
// ---------------------------------------------------------------------------
__global__ __launch_bounds__(256)
void transpose_bf16_kernel(const float* __restrict__ W,
                           unsigned short* __restrict__ Wt, int K, int N) {
  __shared__ float tile[32][33];
  int kb = blockIdx.x * 32, nb = blockIdx.y * 32;
  int tx = threadIdx.x & 31, ty = threadIdx.x >> 5;
#pragma unroll
  for (int i = 0; i < 32; i += 8)
    tile[ty + i][tx] = W[(size_t)(kb + ty + i) * N + nb + tx];
  __syncthreads();
#pragma unroll
  for (int i = 0; i < 32; i += 8)
    Wt[(size_t)(nb + ty + i) * K + kb + tx] = f2bf(tile[tx][ty + i]);
}

// ---------------------------------------------------------------------------
// bf16 MFMA GEMM, double-buffered K-loop:
//   C[M,N] = act(A @ B + bias),  A = [A0 | A1] along K (K0 + (Ktot-K0)),
//   Bt is B transposed: [N][Ktot] bf16 row-major.
// 128x128 tile, BK=32, 256 threads = 4 waves (2x2 of 64x64), 16x16x32 MFMA.
// Per thread, per K-tile: 4 global_load_lds(16B). Prefetch tile k+1 into the
// alternate LDS buffer, then `s_waitcnt vmcnt(4); s_barrier` (raw asm — keeps
// the prefetch in flight across the barrier, unlike __syncthreads' vmcnt(0)).
// ACT: 0 none, 1 relu, 2 tanh, 3 gelu(exact erf)
// ---------------------------------------------------------------------------
template<int ACT>
__global__ __launch_bounds__(256)
void mfma_gemm(const unsigned short* __restrict__ A0,
               const unsigned short* __restrict__ A1, int K0, int Ktot,
               const unsigned short* __restrict__ Bt,
               const float* __restrict__ bias,
               unsigned short* __restrict__ C, int N) {
  __shared__ unsigned short As[2][128 * 32];
  __shared__ unsigned short Bs[2][128 * 32];
  const int tid = threadIdx.x;
  const int wave = tid >> 6, lane = tid & 63;
  const int row0 = blockIdx.y * 128, col0 = blockIdx.x * 128;
  const int wr = wave >> 1, wc = wave & 1;   // wave's 64x64 quadrant

  floatx4 acc[4][4];
#pragma unroll
  for (int u = 0; u < 4; u++)
#pragma unroll
    for (int v = 0; v < 4; v++) acc[u][v] = (floatx4){0.f, 0.f, 0.f, 0.f};

  const int lrow = lane >> 2;       // 0..15
  const int lk = (lane & 3) * 8;    // 0,8,16,24 (bf16 elems; 16B granules)
  const int fm = lane & 15, quad = lane >> 4;

  // issue the 4 per-thread DMA loads for K-tile kt into buffer buf
  auto issue = [&](int kt, int buf) {
    const int k0 = kt * 32;
    const unsigned short* Ap; int kOff, lda;
    if (k0 < K0) { Ap = A0; kOff = k0; lda = K0; }
    else         { Ap = A1; kOff = k0 - K0; lda = Ktot - K0; }
#pragma unroll
    for (int r = 0; r < 2; r++) {
      int srow = r * 64 + wave * 16 + lrow;   // lane-contiguous LDS order
      __builtin_amdgcn_global_load_lds(
          (const __attribute__((address_space(1))) uint32_t*)
              (Ap + (size_t)(row0 + srow) * lda + kOff + lk),
          (__attribute__((address_space(3))) uint32_t*)(&As[buf][srow * 32 + lk]),
          16, 0, 0);
      __builtin_amdgcn_global_load_lds(
          (const __attribute__((address_space(1))) uint32_t*)
              (Bt + (size_t)(col0 + srow) * Ktot + k0 + lk),
          (__attribute__((address_space(3))) uint32_t*)(&Bs[buf][srow * 32 + lk]),
          16, 0, 0);
    }
  };

  const int nk = Ktot >> 5;
  issue(0, 0);
  for (int k = 0; k < nk; k++) {
    const int cur = k & 1;
    if (k + 1 < nk) {
      issue(k + 1, cur ^ 1);
      // wait for tile k's 4 loads only; tile k+1's 4 stay in flight
      asm volatile("s_waitcnt vmcnt(4)\ns_barrier" ::: "memory");
    } else {
      asm volatile("s_waitcnt vmcnt(0)\ns_barrier" ::: "memory");
    }

    bf16x8 a[4], b[4];
#pragma unroll
    for (int u = 0; u < 4; u++)
      a[u] = *(const bf16x8*)(&As[cur][(wr * 64 + u * 16 + fm) * 32 + quad * 8]);
#pragma unroll
    for (int v = 0; v < 4; v++)
      b[v] = *(const bf16x8*)(&Bs[cur][(wc * 64 + v * 16 + fm) * 32 + quad * 8]);
#pragma unroll
    for (int u = 0; u < 4; u++)
#pragma unroll
      for (int v = 0; v < 4; v++)
        acc[u][v] = __builtin_amdgcn_mfma_f32_16x16x32_bf16(a[u], b[v],
                                                            acc[u][v], 0, 0, 0);
    // all waves done reading buf `cur` before next iter's issue overwrites it
    asm volatile("s_barrier" ::: "memory");
  }

  // epilogue: D lane mapping col=lane&15, row=quad*4+reg (m89-verified)
#pragma unroll
  for (int v = 0; v < 4; v++) {
    int col = col0 + wc * 64 + v * 16 + fm;
    float bv = bias[col];
#pragma unroll
    for (int u = 0; u < 4; u++) {
      int rbase = row0 + wr * 64 + u * 16 + quad * 4;
#pragma unroll
      for (int r = 0; r < 4; r++) {
        float val = acc[u][v][r] + bv;
        if (ACT == 1) val = fmaxf(val, 0.0f);
        if (ACT == 2) val = tanhf(val);
        if (ACT == 3) val = 0.5f * val * (1.0f + erff(val * 0.70710678118654752f));
        C[(size_t)(rbase + r) * N + col] = f2bf(val);
      }
    }
  }
}

__global__ void init_normal_kernel(float* __restrict__ x,
                                   unsigned short* __restrict__ xbf,
                                   uint32_t k0, uint32_t k1, int n) {
  int i = blockIdx.x * blockDim.x + threadIdx.x;
  if (i >= n) return;
  float v = tf_normal(k0, k1, (uint32_t)i);
  x[i] = v;
  xbf[i] = f2bf(v);
}

__global__ void update_kernel(float* __restrict__ x,
                              unsigned short* __restrict__ xbf,
                              const unsigned short* __restrict__ d0,
                              const unsigned short* __restrict__ d1,
                              const unsigned short* __restrict__ itf,
                              const float* __restrict__ a_amp,
                              const float* __restrict__ b_amp,
                              const float* __restrict__ ph,
                              float coh, float c1, float sqrt_alpha,
                              float sigma, int add_noise,
                              uint32_t k0, uint32_t k1, int n) {
  int i = blockIdx.x * blockDim.x + threadIdx.x;
  if (i >= n) return;
  float aa = a_amp[0], bb = b_amp[0], pc = ph[0];
  float a2 = aa * aa, b2 = bb * bb, s = a2 + b2;
  float p0 = a2 / s, p1 = b2 / s;
  float qi = 2.0f * sqrtf(p0 * p1) * pc * coh;
  float den = sqrtf(p0) * bf2f(d0[i]) + sqrtf(p1) * bf2f(d1[i])
            + qi * bf2f(itf[i]);
  float xn = (x[i] - c1 * den) / sqrt_alpha;
  if (add_noise) {
    float nz = tf_normal(k0, k1, (uint32_t)i);
    xn += (sigma + 0.1f * fabsf(qi)) * nz;
  }
  x[i] = xn;
  xbf[i] = f2bf(xn);
}

__global__ void final_kernel(const float* __restrict__ x,
                             const float* __restrict__ real,
                             float* __restrict__ out,
                             const float* __restrict__ a_amp,
                             const float* __restrict__ b_amp,
                             uint32_t k0, uint32_t k1, int n) {
  int i = blockIdx.x * blockDim.x + threadIdx.x;
  if (i >= n) return;
  float aa = a_amp[0], bb = b_amp[0];
  float a2 = aa * aa, b2 = bb * bb;
  float p0 = a2 / (a2 + b2);
  uint32_t o0, o1;
  tf2x32(k0, k1, 0u, 0u, o0, o1);
  uint32_t bits = o0 ^ o1;
  float u = __uint_as_float(0x3F800000u | (bits >> 9)) - 1.0f;
  float xv = x[i];
  out[i] = (u < p0) ? (0.7f * xv + 0.3f * real[i]) : xv;
}

extern "C" void kernel_launch(void* const* d_in, const int* in_sizes, int n_in,
                              void* d_out, int out_size, void* d_ws,
                              size_t ws_size, hipStream_t stream) {
  const float* real = (const float*)d_in[0];
  const float* Wq  = (const float*)d_in[2];
  const float* bq  = (const float*)d_in[3];
  const float* W01 = (const float*)d_in[4];
  const float* b01 = (const float*)d_in[5];
  const float* W02 = (const float*)d_in[6];
  const float* b02 = (const float*)d_in[7];
  const float* W11 = (const float*)d_in[8];
  const float* b11 = (const float*)d_in[9];
  const float* W12 = (const float*)d_in[10];
  const float* b12 = (const float*)d_in[11];
  const float* Wi1 = (const float*)d_in[12];
  const float* bi1 = (const float*)d_in[13];
  const float* Wi2 = (const float*)d_in[14];
  const float* bi2 = (const float*)d_in[15];
  const float* a_amp = (const float*)d_in[16];
  const float* b_amp = (const float*)d_in[17];
  const float* ph    = (const float*)d_in[18];

  const int Nn = 8192, F = 512, H = 1024;
  const int nElem = Nn * F;  // 4,194,304

  // workspace layout
  char* ws = (char*)d_ws;
  float* x = (float*)ws;                                   ws += (size_t)nElem * 4;
  unsigned short* xbf = (unsigned short*)ws;               ws += (size_t)nElem * 2;
  unsigned short* qf  = (unsigned short*)ws;               ws += (size_t)Nn * H * 2;
  unsigned short* h0  = (unsigned short*)ws;               ws += (size_t)Nn * H * 2;
  unsigned short* h1  = (unsigned short*)ws;               ws += (size_t)Nn * H * 2;
  unsigned short* d0  = (unsigned short*)ws;               ws += (size_t)nElem * 2;
  unsigned short* d1  = (unsigned short*)ws;               ws += (size_t)nElem * 2;
  unsigned short* itf = (unsigned short*)ws;               ws += (size_t)nElem * 2;
  unsigned short* Wq_t  = (unsigned short*)ws;             ws += (size_t)F * H * 2;
  unsigned short* W01_t = (unsigned short*)ws;             ws += (size_t)H * H * 2;
  unsigned short* W11_t = (unsigned short*)ws;             ws += (size_t)H * H * 2;
  unsigned short* W02_t = (unsigned short*)ws;             ws += (size_t)H * F * 2;
  unsigned short* W12_t = (unsigned short*)ws;             ws += (size_t)H * F * 2;
  unsigned short* Wi1_t = (unsigned short*)ws;             ws += (size_t)(2 * F) * H * 2;
  unsigned short* Wi2_t = (unsigned short*)ws;             ws += (size_t)H * F * 2;

  dim3 tb(256);
  transpose_bf16_kernel<<<dim3(F / 32, H / 32), tb, 0, stream>>>(Wq, Wq_t, F, H);
  transpose_bf16_kernel<<<dim3(H / 32, H / 32), tb, 0, stream>>>(W01, W01_t, H, H);
  transpose_bf16_kernel<<<dim3(H / 32, H / 32), tb, 0, stream>>>(W11, W11_t, H, H);
  transpose_bf16_kernel<<<dim3(H / 32, F / 32), tb, 0, stream>>>(W02, W02_t, H, F);
  transpose_bf16_kernel<<<dim3(H / 32, F / 32), tb, 0, stream>>>(W12, W12_t, H, F);
  transpose_bf16_kernel<<<dim3(2 * F / 32, H / 32), tb, 0, stream>>>(Wi1, Wi1_t, 2 * F, H);
  transpose_bf16_kernel<<<dim3(H / 32, F / 32), tb, 0, stream>>>(Wi2, Wi2_t, H, F);

  uint32_t kx0, kx1; tf2x32(0u, 1u, 0u, 10000u, kx0, kx1);
  init_normal_kernel<<<(nElem + 255) / 256, 256, 0, stream>>>(x, xbf, kx0, kx1, nElem);

  float sched[100];
  for (int i = 0; i < 100; i++)
    sched[i] = (float)(1e-4 + (0.02 - 1e-4) * (double)i / 99.0);
  const float decay = expf(-0.1f);
  float coh = 1.0f;

  dim3 blk(256);
  dim3 gH(H / 128, Nn / 128);  // 512 blocks (N=1024 outputs)
  dim3 gF(F / 128, Nn / 128);  // 256 blocks (N=512 outputs)

  for (int j = 0; j < 50; j++) {
    int t = 49 - j;
    // qf = relu(x @ Wq + bq)
    mfma_gemm<1><<<gH, blk, 0, stream>>>(xbf, xbf, F, F, Wq_t, bq, qf, H);
    // h0 = relu(qf @ W01 + b01); h1 = tanh(qf @ W11 + b11)
    mfma_gemm<1><<<gH, blk, 0, stream>>>(qf, qf, H, H, W01_t, b01, h0, H);
    mfma_gemm<2><<<gH, blk, 0, stream>>>(qf, qf, H, H, W11_t, b11, h1, H);
    // d0 = h0 @ W02 + b02; d1 = h1 @ W12 + b12
    mfma_gemm<0><<<gF, blk, 0, stream>>>(h0, h0, H, H, W02_t, b02, d0, F);
    mfma_gemm<0><<<gF, blk, 0, stream>>>(h1, h1, H, H, W12_t, b12, d1, F);
    // qf (reused) = gelu([d0|d1] @ Wi1 + bi1)
    mfma_gemm<3><<<gH, blk, 0, stream>>>(d0, d1, F, 2 * F, Wi1_t, bi1, qf, H);
    // itf = qf @ Wi2 + bi2
    mfma_gemm<0><<<gF, blk, 0, stream>>>(qf, qf, H, H, Wi2_t, bi2, itf, F);

    float schedt = sched[t];
    float alphaf = fmaxf(1.0f - schedt, 1e-8f);
    float one_m_alpha = 1.0f - alphaf;
    float sqrt_1ma = sqrtf(fmaxf(one_m_alpha, 1e-8f));
    float c1 = one_m_alpha / sqrt_1ma;
    float sqa = sqrtf(alphaf);
    float sigma = 0.0f;
    if (t > 0) {
      float ap = 1.0f - sched[t - 1];
      sigma = sqrtf(fmaxf((1.0f - ap) / one_m_alpha * (1.0f - alphaf / ap), 0.0f));
    }
    uint32_t kt0, kt1; tf2x32(0u, 1u, 0u, (uint32_t)t, kt0, kt1);
    update_kernel<<<(nElem + 255) / 256, 256, 0, stream>>>(
        x, xbf, d0, d1, itf, a_amp, b_amp, ph, coh, c1, sqa, sigma,
        (t > 0) ? 1 : 0, kt0, kt1, nElem);
    coh *= decay;
  }

  uint32_t ku0, ku1; tf2x32(0u, 1u, 0u, 99999u, ku0, ku1);
  final_kernel<<<(nElem + 255) / 256, 256, 0, stream>>>(
      x, real, (float*)d_out, a_amp, b_amp, ku0, ku1, nElem);
}

// Round 5
// 9415.691 us; speedup vs baseline: 1.4997x; 1.1757x over previous
//
#include <hip/hip_runtime.h>
#include <stdint.h>
#include <math.h>

// ---------------------------------------------------------------------------
// QuantumDiffusionDreamer — round 5: r4 dbuf core + XCD-aware block swizzle
// (col-blocks of one row-block share an XCD -> A-tiles L2-local) + safe
// merges: [W01|W11] one N=2048 GEMM (block-uniform relu/tanh, separate h0/h1
// outputs), z-batched W02/W12 pair. 6 dispatches/step.
// PRNG: JAX threefry2x32 partitionable (verified r1-r4). x stays fp32.
// ---------------------------------------------------------------------------

typedef __bf16 bf16x8 __attribute__((ext_vector_type(8)));
typedef float floatx4 __attribute__((ext_vector_type(4)));

__host__ __device__ inline void tf2x32(uint32_t k0, uint32_t k1,
                                       uint32_t x0, uint32_t x1,
                                       uint32_t& o0, uint32_t& o1) {
  uint32_t ks2 = k0 ^ k1 ^ 0x1BD11BDAu;
#define TF_R(r) { x0 += x1; x1 = (x1 << (r)) | (x1 >> (32 - (r))); x1 ^= x0; }
  x0 += k0; x1 += k1;
  TF_R(13) TF_R(15) TF_R(26) TF_R(6)
  x0 += k1;  x1 += ks2 + 1u;
  TF_R(17) TF_R(29) TF_R(16) TF_R(24)
  x0 += ks2; x1 += k0 + 2u;
  TF_R(13) TF_R(15) TF_R(26) TF_R(6)
  x0 += k0;  x1 += k1 + 3u;
  TF_R(17) TF_R(29) TF_R(16) TF_R(24)
  x0 += k1;  x1 += ks2 + 4u;
  TF_R(13) TF_R(15) TF_R(26) TF_R(6)
  x0 += ks2; x1 += k0 + 5u;
#undef TF_R
  o0 = x0; o1 = x1;
}

__device__ inline float erfinv_f32(float x) {
  float w = -log1pf(-x * x);
  float p;
  if (w < 5.0f) {
    w = w - 2.5f;
    p = 2.81022636e-08f;
    p = fmaf(p, w, 3.43273939e-07f);
    p = fmaf(p, w, -3.5233877e-06f);
    p = fmaf(p, w, -4.39150654e-06f);
    p = fmaf(p, w, 0.00021858087f);
    p = fmaf(p, w, -0.00125372503f);
    p = fmaf(p, w, -0.00417768164f);
    p = fmaf(p, w, 0.246640727f);
    p = fmaf(p, w, 1.50140941f);
  } else {
    w = sqrtf(w) - 3.0f;
    p = -0.000200214257f;
    p = fmaf(p, w, 0.000100950558f);
    p = fmaf(p, w, 0.00134934322f);
    p = fmaf(p, w, -0.00367342844f);
    p = fmaf(p, w, 0.00573950773f);
    p = fmaf(p, w, -0.0076224613f);
    p = fmaf(p, w, 0.00943887047f);
    p = fmaf(p, w, 1.00167406f);
    p = fmaf(p, w, 2.83297682f);
  }
  return p * x;
}

__device__ inline float tf_normal(uint32_t k0, uint32_t k1, uint32_t i) {
  uint32_t o0, o1;
  tf2x32(k0, k1, 0u, i, o0, o1);
  uint32_t bits = o0 ^ o1;  // partitionable random_bits path
  float f = __uint_as_float(0x3F800000u | (bits >> 9)) - 1.0f;  // [0,1)
  float u = f * 2.0f + (-0.99999994f);
  u = fmaxf(-0.99999994f, u);
  return 1.41421356f * erfinv_f32(u);
}

__device__ inline unsigned short f2bf(float f) {
  uint32_t u = __float_as_uint(f);
  u += 0x7FFFu + ((u >> 16) & 1u);   // round-to-nearest-even
  return (unsigned short)(u >> 16);
}
__device__ inline float bf2f(unsigned short h) {
  return __uint_as_float(((uint32_t)h) << 16);
}

// ---------------------------------------------------------------------------
// Weight transpose + bf16 convert: Wt[n][k] = bf16(W[k][n]);  W is [K,N] fp32.
// ---------------------------------------------------------------------------
__global__ __launch_bounds__(256)
void transpose_bf16_kernel(const float* __restrict__ W,
                           unsigned short* __restrict__ Wt, int K, int N) {
  __shared__ float tile[32][33];
  int kb = blockIdx.x * 32, nb = blockIdx.y * 32;
  int tx = threadIdx.x & 31, ty = threadIdx.x >> 5;
#pragma unroll
  for (int i = 0; i < 32; i += 8)
    tile[ty + i][tx] = W[(size_t)(kb + ty + i) * N + nb + tx];
  __syncthreads();
#pragma unroll
  for (int i = 0; i < 32; i += 8)
    Wt[(size_t)(nb + ty + i) * K + kb + tx] = f2bf(tile[tx][ty + i]);
}

// ---------------------------------------------------------------------------
// Double-buffered MFMA core (r4, measured best).  A = [A0|A1] along K.
// 128x128 tile, BK=32, 4 waves, 16x16x32 bf16 MFMA, global_load_lds(16B),
// raw `s_waitcnt vmcnt(4); s_barrier` keeps next tile's loads in flight.
// ---------------------------------------------------------------------------
__device__ __forceinline__ void gemm_core_db(
    const unsigned short* __restrict__ A0, const unsigned short* __restrict__ A1,
    int lda0, int lda1, int K0, int Ktot,
    const unsigned short* __restrict__ Bt,
    int row0, int col0,
    unsigned short (*As)[128 * 32], unsigned short (*Bs)[128 * 32],
    floatx4 (&acc)[4][4]) {
  const int tid = threadIdx.x;
  const int wave = tid >> 6, lane = tid & 63;
  const int wr = wave >> 1, wc = wave & 1;
  const int lrow = lane >> 2;       // 0..15
  const int lk = (lane & 3) * 8;    // 0,8,16,24
  const int fm = lane & 15, quad = lane >> 4;

  auto issue = [&](int kt, int buf) {
    const int k0 = kt * 32;
    const unsigned short* Ap; int kOff, lda;
    if (k0 < K0) { Ap = A0; kOff = k0; lda = lda0; }
    else         { Ap = A1; kOff = k0 - K0; lda = lda1; }
#pragma unroll
    for (int r = 0; r < 2; r++) {
      int srow = r * 64 + wave * 16 + lrow;   // lane-contiguous LDS order
      __builtin_amdgcn_global_load_lds(
          (const __attribute__((address_space(1))) uint32_t*)
              (Ap + (size_t)(row0 + srow) * lda + kOff + lk),
          (__attribute__((address_space(3))) uint32_t*)(&As[buf][srow * 32 + lk]),
          16, 0, 0);
      __builtin_amdgcn_global_load_lds(
          (const __attribute__((address_space(1))) uint32_t*)
              (Bt + (size_t)(col0 + srow) * Ktot + k0 + lk),
          (__attribute__((address_space(3))) uint32_t*)(&Bs[buf][srow * 32 + lk]),
          16, 0, 0);
    }
  };

  const int nk = Ktot >> 5;
  issue(0, 0);
  for (int k = 0; k < nk; k++) {
    const int cur = k & 1;
    if (k + 1 < nk) {
      issue(k + 1, cur ^ 1);
      asm volatile("s_waitcnt vmcnt(4)\ns_barrier" ::: "memory");
    } else {
      asm volatile("s_waitcnt vmcnt(0)\ns_barrier" ::: "memory");
    }
    bf16x8 a[4], b[4];
#pragma unroll
    for (int u = 0; u < 4; u++)
      a[u] = *(const bf16x8*)(&As[cur][(wr * 64 + u * 16 + fm) * 32 + quad * 8]);
#pragma unroll
    for (int v = 0; v < 4; v++)
      b[v] = *(const bf16x8*)(&Bs[cur][(wc * 64 + v * 16 + fm) * 32 + quad * 8]);
#pragma unroll
    for (int u = 0; u < 4; u++)
#pragma unroll
      for (int v = 0; v < 4; v++)
        acc[u][v] = __builtin_amdgcn_mfma_f32_16x16x32_bf16(a[u], b[v],
                                                            acc[u][v], 0, 0, 0);
    asm volatile("s_barrier" ::: "memory");
  }
}

// XCD-aware swizzle: gy is always 64 (M=8192). by = id%64, bx = id/64 makes
// all col-blocks of one row-block share id%8 -> same XCD (dispatch heuristic,
// performance-only). A row-block then stays in that XCD's L2.
__device__ __forceinline__ void swizzled_block(int& row0, int& col0) {
  int id = blockIdx.x + gridDim.x * blockIdx.y;
  row0 = (id & 63) << 7;
  col0 = (id >> 6) << 7;
}

// Generic GEMM. ACT: 0 none, 1 relu, 2 tanh, 3 gelu(exact),
// 4 = split epilogue: cols < nsplit -> relu+bias0 -> C0; else tanh+bias1 -> C1
// (nsplit multiple of 128 -> block-uniform side select).
template<int ACT>
__global__ __launch_bounds__(256)
void mfma_gemm(const unsigned short* __restrict__ A0,
               const unsigned short* __restrict__ A1,
               int lda0, int lda1, int K0, int Ktot,
               const unsigned short* __restrict__ Bt,
               const float* __restrict__ bias0,
               const float* __restrict__ bias1, int nsplit,
               unsigned short* __restrict__ C0,
               unsigned short* __restrict__ C1, int ldc) {
  __shared__ unsigned short As[2][128 * 32];
  __shared__ unsigned short Bs[2][128 * 32];
  int row0, col0;
  swizzled_block(row0, col0);
  floatx4 acc[4][4];
#pragma unroll
  for (int u = 0; u < 4; u++)
#pragma unroll
    for (int v = 0; v < 4; v++) acc[u][v] = (floatx4){0.f, 0.f, 0.f, 0.f};
  gemm_core_db(A0, A1, lda0, lda1, K0, Ktot, Bt, row0, col0, As, Bs, acc);

  const int lane = threadIdx.x & 63, wave = threadIdx.x >> 6;
  const int wr = wave >> 1, wc = wave & 1;
  const int fm = lane & 15, quad = lane >> 4;
  const bool side = (ACT == 4) && (col0 >= nsplit);
  const float* bias = side ? bias1 : bias0;
  unsigned short* C = side ? C1 : C0;
  const int cbase = col0 - (side ? nsplit : 0);
#pragma unroll
  for (int v = 0; v < 4; v++) {
    int col = cbase + wc * 64 + v * 16 + fm;
    float bv = bias[col];
#pragma unroll
    for (int u = 0; u < 4; u++) {
      int rbase = row0 + wr * 64 + u * 16 + quad * 4;
#pragma unroll
      for (int r = 0; r < 4; r++) {
        float val = acc[u][v][r] + bv;
        if (ACT == 1) val = fmaxf(val, 0.0f);
        if (ACT == 2) val = tanhf(val);
        if (ACT == 3) val = 0.5f * val * (1.0f + erff(val * 0.70710678118654752f));
        if (ACT == 4) val = side ? tanhf(val) : fmaxf(val, 0.0f);
        C[(size_t)(rbase + r) * ldc + col] = f2bf(val);
      }
    }
  }
}

// z-batched pair of independent GEMMs (same shapes): z=0 (Aa,Bta,biasa->Ca),
// z=1 (Ab,Btb,biasb->Cb). No activation.
__global__ __launch_bounds__(256)
void mfma_gemm_pair(const unsigned short* __restrict__ Aa,
                    const unsigned short* __restrict__ Ab,
                    const unsigned short* __restrict__ Bta,
                    const unsigned short* __restrict__ Btb,
                    const float* __restrict__ biasa,
                    const float* __restrict__ biasb,
                    unsigned short* __restrict__ Ca,
                    unsigned short* __restrict__ Cb,
                    int Ktot, int ldc) {
  __shared__ unsigned short As[2][128 * 32];
  __shared__ unsigned short Bs[2][128 * 32];
  const int z = blockIdx.z;
  const unsigned short* A = z ? Ab : Aa;
  const unsigned short* Bt = z ? Btb : Bta;
  const float* bias = z ? biasb : biasa;
  unsigned short* C = z ? Cb : Ca;
  int row0, col0;
  swizzled_block(row0, col0);
  floatx4 acc[4][4];
#pragma unroll
  for (int u = 0; u < 4; u++)
#pragma unroll
    for (int v = 0; v < 4; v++) acc[u][v] = (floatx4){0.f, 0.f, 0.f, 0.f};
  gemm_core_db(A, A, Ktot, Ktot, Ktot, Ktot, Bt, row0, col0, As, Bs, acc);

  const int lane = threadIdx.x & 63, wave = threadIdx.x >> 6;
  const int wr = wave >> 1, wc = wave & 1;
  const int fm = lane & 15, quad = lane >> 4;
#pragma unroll
  for (int v = 0; v < 4; v++) {
    int col = col0 + wc * 64 + v * 16 + fm;
    float bv = bias[col];
#pragma unroll
    for (int u = 0; u < 4; u++) {
      int rbase = row0 + wr * 64 + u * 16 + quad * 4;
#pragma unroll
      for (int r = 0; r < 4; r++)
        C[(size_t)(rbase + r) * ldc + col] = f2bf(acc[u][v][r] + bv);
    }
  }
}

__global__ void init_normal_kernel(float* __restrict__ x,
                                   unsigned short* __restrict__ xbf,
                                   uint32_t k0, uint32_t k1, int n) {
  int i = blockIdx.x * blockDim.x + threadIdx.x;
  if (i >= n) return;
  float v = tf_normal(k0, k1, (uint32_t)i);
  x[i] = v;
  xbf[i] = f2bf(v);
}

__global__ void update_kernel(float* __restrict__ x,
                              unsigned short* __restrict__ xbf,
                              const unsigned short* __restrict__ d0,
                              const unsigned short* __restrict__ d1,
                              const unsigned short* __restrict__ itf,
                              const float* __restrict__ a_amp,
                              const float* __restrict__ b_amp,
                              const float* __restrict__ ph,
                              float coh, float c1, float sqrt_alpha,
                              float sigma, int add_noise,
                              uint32_t k0, uint32_t k1, int n) {
  int i = blockIdx.x * blockDim.x + threadIdx.x;
  if (i >= n) return;
  float aa = a_amp[0], bb = b_amp[0], pc = ph[0];
  float a2 = aa * aa, b2 = bb * bb, s = a2 + b2;
  float p0 = a2 / s, p1 = b2 / s;
  float qi = 2.0f * sqrtf(p0 * p1) * pc * coh;
  float den = sqrtf(p0) * bf2f(d0[i]) + sqrtf(p1) * bf2f(d1[i])
            + qi * bf2f(itf[i]);
  float xn = (x[i] - c1 * den) / sqrt_alpha;
  if (add_noise) {
    float nz = tf_normal(k0, k1, (uint32_t)i);
    xn += (sigma + 0.1f * fabsf(qi)) * nz;
  }
  x[i] = xn;
  xbf[i] = f2bf(xn);
}

__global__ void final_kernel(const float* __restrict__ x,
                             const float* __restrict__ real,
                             float* __restrict__ out,
                             const float* __restrict__ a_amp,
                             const float* __restrict__ b_amp,
                             uint32_t k0, uint32_t k1, int n) {
  int i = blockIdx.x * blockDim.x + threadIdx.x;
  if (i >= n) return;
  float aa = a_amp[0], bb = b_amp[0];
  float a2 = aa * aa, b2 = bb * bb;
  float p0 = a2 / (a2 + b2);
  uint32_t o0, o1;
  tf2x32(k0, k1, 0u, 0u, o0, o1);
  uint32_t bits = o0 ^ o1;
  float u = __uint_as_float(0x3F800000u | (bits >> 9)) - 1.0f;
  float xv = x[i];
  out[i] = (u < p0) ? (0.7f * xv + 0.3f * real[i]) : xv;
}

extern "C" void kernel_launch(void* const* d_in, const int* in_sizes, int n_in,
                              void* d_out, int out_size, void* d_ws,
                              size_t ws_size, hipStream_t stream) {
  const float* real = (const float*)d_in[0];
  const float* Wq  = (const float*)d_in[2];
  const float* bq  = (const float*)d_in[3];
  const float* W01 = (const float*)d_in[4];
  const float* b01 = (const float*)d_in[5];
  const float* W02 = (const float*)d_in[6];
  const float* b02 = (const float*)d_in[7];
  const float* W11 = (const float*)d_in[8];
  const float* b11 = (const float*)d_in[9];
  const float* W12 = (const float*)d_in[10];
  const float* b12 = (const float*)d_in[11];
  const float* Wi1 = (const float*)d_in[12];
  const float* bi1 = (const float*)d_in[13];
  const float* Wi2 = (const float*)d_in[14];
  const float* bi2 = (const float*)d_in[15];
  const float* a_amp = (const float*)d_in[16];
  const float* b_amp = (const float*)d_in[17];
  const float* ph    = (const float*)d_in[18];

  const int Nn = 8192, F = 512, H = 1024;
  const int nElem = Nn * F;  // 4,194,304
  const int NSPLIT_OFF = 1 << 30;

  // workspace layout
  char* ws = (char*)d_ws;
  float* x = (float*)ws;                                   ws += (size_t)nElem * 4;
  unsigned short* xbf = (unsigned short*)ws;               ws += (size_t)nElem * 2;
  unsigned short* qf  = (unsigned short*)ws;               ws += (size_t)Nn * H * 2;
  unsigned short* h0  = (unsigned short*)ws;               ws += (size_t)Nn * H * 2;
  unsigned short* h1  = (unsigned short*)ws;               ws += (size_t)Nn * H * 2;
  unsigned short* d0  = (unsigned short*)ws;               ws += (size_t)nElem * 2;
  unsigned short* d1  = (unsigned short*)ws;               ws += (size_t)nElem * 2;
  unsigned short* itf = (unsigned short*)ws;               ws += (size_t)nElem * 2;
  unsigned short* Wq_t  = (unsigned short*)ws;             ws += (size_t)F * H * 2;
  unsigned short* WA_t  = (unsigned short*)ws;             ws += (size_t)(2 * H) * H * 2; // [W01_t ; W11_t]
  unsigned short* W02_t = (unsigned short*)ws;             ws += (size_t)H * F * 2;
  unsigned short* W12_t = (unsigned short*)ws;             ws += (size_t)H * F * 2;
  unsigned short* Wi1_t = (unsigned short*)ws;             ws += (size_t)(2 * F) * H * 2;
  unsigned short* Wi2_t = (unsigned short*)ws;             ws += (size_t)H * F * 2;

  dim3 tb(256);
  transpose_bf16_kernel<<<dim3(F / 32, H / 32), tb, 0, stream>>>(Wq, Wq_t, F, H);
  transpose_bf16_kernel<<<dim3(H / 32, H / 32), tb, 0, stream>>>(W01, WA_t, H, H);
  transpose_bf16_kernel<<<dim3(H / 32, H / 32), tb, 0, stream>>>(W11, WA_t + (size_t)H * H, H, H);
  transpose_bf16_kernel<<<dim3(H / 32, F / 32), tb, 0, stream>>>(W02, W02_t, H, F);
  transpose_bf16_kernel<<<dim3(H / 32, F / 32), tb, 0, stream>>>(W12, W12_t, H, F);
  transpose_bf16_kernel<<<dim3(2 * F / 32, H / 32), tb, 0, stream>>>(Wi1, Wi1_t, 2 * F, H);
  transpose_bf16_kernel<<<dim3(H / 32, F / 32), tb, 0, stream>>>(Wi2, Wi2_t, H, F);

  uint32_t kx0, kx1; tf2x32(0u, 1u, 0u, 10000u, kx0, kx1);
  init_normal_kernel<<<(nElem + 255) / 256, 256, 0, stream>>>(x, xbf, kx0, kx1, nElem);

  float sched[100];
  for (int i = 0; i < 100; i++)
    sched[i] = (float)(1e-4 + (0.02 - 1e-4) * (double)i / 99.0);
  const float decay = expf(-0.1f);
  float coh = 1.0f;

  dim3 blk(256);
  dim3 g1(H / 128, 64);            // 512 blocks
  dim3 g2(2 * H / 128, 64);        // 1024 blocks
  dim3 g45(F / 128, 64, 2);        // 512 blocks
  dim3 g6(H / 128, 64);            // 512 blocks
  dim3 g7(F / 128, 64);            // 256 blocks

  for (int j = 0; j < 50; j++) {
    int t = 49 - j;
    // G1: qf = relu(x @ Wq + bq)
    mfma_gemm<1><<<g1, blk, 0, stream>>>(xbf, xbf, F, F, F, F, Wq_t,
                                         bq, nullptr, NSPLIT_OFF, qf, nullptr, H);
    // G2 merged: h0 = relu(qf@W01+b01), h1 = tanh(qf@W11+b11) in one N=2048 GEMM
    mfma_gemm<4><<<g2, blk, 0, stream>>>(qf, qf, H, H, H, H, WA_t,
                                         b01, b11, H, h0, h1, H);
    // G4/G5 z-batched: d0 = h0@W02+b02 ; d1 = h1@W12+b12
    mfma_gemm_pair<<<g45, blk, 0, stream>>>(h0, h1, W02_t, W12_t, b02, b12,
                                            d0, d1, H, F);
    // G6: qf(reused) = gelu([d0|d1] @ Wi1 + bi1)
    mfma_gemm<3><<<g6, blk, 0, stream>>>(d0, d1, F, F, F, 2 * F, Wi1_t,
                                         bi1, nullptr, NSPLIT_OFF, qf, nullptr, H);
    // G7: itf = qf @ Wi2 + bi2
    mfma_gemm<0><<<g7, blk, 0, stream>>>(qf, qf, H, H, H, H, Wi2_t,
                                         bi2, nullptr, NSPLIT_OFF, itf, nullptr, F);

    float schedt = sched[t];
    float alphaf = fmaxf(1.0f - schedt, 1e-8f);
    float one_m_alpha = 1.0f - alphaf;
    float sqrt_1ma = sqrtf(fmaxf(one_m_alpha, 1e-8f));
    float c1 = one_m_alpha / sqrt_1ma;
    float sqa = sqrtf(alphaf);
    float sigma = 0.0f;
    if (t > 0) {
      float ap = 1.0f - sched[t - 1];
      sigma = sqrtf(fmaxf((1.0f - ap) / one_m_alpha * (1.0f - alphaf / ap), 0.0f));
    }
    uint32_t kt0, kt1; tf2x32(0u, 1u, 0u, (uint32_t)t, kt0, kt1);
    update_kernel<<<(nElem + 255) / 256, 256, 0, stream>>>(
        x, xbf, d0, d1, itf, a_amp, b_amp, ph, coh, c1, sqa, sigma,
        (t > 0) ? 1 : 0, kt0, kt1, nElem);
    coh *= decay;
  }

  uint32_t ku0, ku1; tf2x32(0u, 1u, 0u, 99999u, ku0, ku1);
  final_kernel<<<(nElem + 255) / 256, 256, 0, stream>>>(
      x, real, (float*)d_out, a_amp, b_amp, ku0, ku1, nElem);
}